// Round 4
// 409.963 us; speedup vs baseline: 1.1329x; 1.1329x over previous
//
#include <hip/hip_runtime.h>

// DFTB Slater-Koster table interpolation.
// Inputs (setup_inputs order):
//   0: rij            [E=2,000,000] float32
//   1: edge_type      [E]           int32
//   2: atom_type      [N=500,000]   int32
//   3: hopping_tables [10,16,512]   float32
//   4: overlap_tables [10,16,512]   float32
//   5: onsiteE        [4,4]         float32
// Outputs (concatenated flat):
//   edge_features [E,16], edge_overlap [E,16], node_features [N,4]
//
// Strategy: tables are repacked into workspace as packed[B][G][32]
// (per grid point g: 16 hop floats then 16 ovl floats = one 128-B row).
// Each edge thread then reads rows i0 and i0+1 -> 256 contiguous bytes
// via 16 dwordx4 loads, instead of 64 stride-2KB scalar gathers.

#define NGRID 512
#define NUM_INGRLS 16
#define N_BOND_TYPES 10
#define PACKED_FLOATS (N_BOND_TYPES * NGRID * 32)          // 163,840 floats
#define PACKED_BYTES  (PACKED_FLOATS * sizeof(float))      // 655,360 B

// Native 4-float vector type (clang ext vector) — required for
// __builtin_nontemporal_store, and layout-compatible with float4.
typedef float fx4 __attribute__((ext_vector_type(4)));

__global__ __launch_bounds__(256) void repack_tables(
    const float* __restrict__ hop,
    const float* __restrict__ ovl,
    float* __restrict__ packed)
{
    int t = blockIdx.x * blockDim.x + threadIdx.x;
    if (t >= N_BOND_TYPES * NGRID * NUM_INGRLS) return;
    int m = t & (NUM_INGRLS - 1);
    int g = (t >> 4) & (NGRID - 1);
    int b = t >> 13;                       // 16*512 = 8192 = 2^13
    float h = hop[((size_t)b * NUM_INGRLS + m) * NGRID + g];
    float o = ovl[((size_t)b * NUM_INGRLS + m) * NGRID + g];
    size_t row = ((size_t)b * NGRID + g) * 32;
    packed[row + m]      = h;
    packed[row + 16 + m] = o;
}

__device__ __forceinline__ fx4 lerp4(fx4 a, fx4 b, float w0, float w1) {
    return a * w0 + b * w1;
}

__global__ __launch_bounds__(256) void dftb_edge_packed(
    const float* __restrict__ rij,
    const int*   __restrict__ etype,
    const float* __restrict__ packed,   // [10][512][32]
    float* __restrict__ out_hop,
    float* __restrict__ out_ovl,
    int E)
{
    const float X0f = 1.0f;
    const float DXf = (float)((10.0 - 1.0) / (NGRID - 1));

    int e = blockIdx.x * blockDim.x + threadIdx.x;
    if (e >= E) return;

    float r = rij[e];
    int   b = etype[e];

    float t  = (r - X0f) / DXf;
    int   i0 = (int)floorf(t);
    i0 = min(max(i0, 0), NGRID - 2);
    float frac = t - (float)i0;
    float w0   = 1.0f - frac;

    const fx4* row0 = (const fx4*)(packed + ((size_t)b * NGRID + i0) * 32);
    // row0[0..3]  : hop at grid i0     row0[4..7]  : ovl at grid i0
    // row0[8..11] : hop at grid i0+1   row0[12..15]: ovl at grid i0+1

    fx4 h00 = row0[0],  h01 = row0[1],  h02 = row0[2],  h03 = row0[3];
    fx4 h10 = row0[8],  h11 = row0[9],  h12 = row0[10], h13 = row0[11];
    fx4 o00 = row0[4],  o01 = row0[5],  o02 = row0[6],  o03 = row0[7];
    fx4 o10 = row0[12], o11 = row0[13], o12 = row0[14], o13 = row0[15];

    fx4* oh4 = (fx4*)(out_hop + (size_t)e * NUM_INGRLS);
    fx4* oo4 = (fx4*)(out_ovl + (size_t)e * NUM_INGRLS);

    __builtin_nontemporal_store(lerp4(h00, h10, w0, frac), oh4 + 0);
    __builtin_nontemporal_store(lerp4(h01, h11, w0, frac), oh4 + 1);
    __builtin_nontemporal_store(lerp4(h02, h12, w0, frac), oh4 + 2);
    __builtin_nontemporal_store(lerp4(h03, h13, w0, frac), oh4 + 3);
    __builtin_nontemporal_store(lerp4(o00, o10, w0, frac), oo4 + 0);
    __builtin_nontemporal_store(lerp4(o01, o11, w0, frac), oo4 + 1);
    __builtin_nontemporal_store(lerp4(o02, o12, w0, frac), oo4 + 2);
    __builtin_nontemporal_store(lerp4(o03, o13, w0, frac), oo4 + 3);
}

// Fallback (original layout) if workspace is too small for the packed table.
__global__ __launch_bounds__(256) void dftb_edge_kernel(
    const float* __restrict__ rij,
    const int*   __restrict__ etype,
    const float* __restrict__ hop,
    const float* __restrict__ ovl,
    float* __restrict__ out_hop,
    float* __restrict__ out_ovl,
    int E)
{
    const float X0f = 1.0f;
    const float DXf = (float)((10.0 - 1.0) / (NGRID - 1));

    int e = blockIdx.x * blockDim.x + threadIdx.x;
    if (e >= E) return;

    float r = rij[e];
    int   b = etype[e];

    float t  = (r - X0f) / DXf;
    int   i0 = (int)floorf(t);
    i0 = min(max(i0, 0), NGRID - 2);
    float frac = t - (float)i0;
    float w0   = 1.0f - frac;

    const float* hbase = hop + (size_t)b * (NUM_INGRLS * NGRID) + i0;
    const float* obase = ovl + (size_t)b * (NUM_INGRLS * NGRID) + i0;

    float oh[NUM_INGRLS];
    float oo[NUM_INGRLS];
#pragma unroll
    for (int m = 0; m < NUM_INGRLS; ++m) {
        float y0 = hbase[m * NGRID];
        float y1 = hbase[m * NGRID + 1];
        oh[m] = y0 * w0 + y1 * frac;
        float z0 = obase[m * NGRID];
        float z1 = obase[m * NGRID + 1];
        oo[m] = z0 * w0 + z1 * frac;
    }

    float4* oh4 = (float4*)(out_hop + (size_t)e * NUM_INGRLS);
    float4* oo4 = (float4*)(out_ovl + (size_t)e * NUM_INGRLS);
#pragma unroll
    for (int q = 0; q < 4; ++q) {
        oh4[q] = make_float4(oh[4*q+0], oh[4*q+1], oh[4*q+2], oh[4*q+3]);
        oo4[q] = make_float4(oo[4*q+0], oo[4*q+1], oo[4*q+2], oo[4*q+3]);
    }
}

__global__ __launch_bounds__(256) void dftb_node_kernel(
    const int*   __restrict__ atype,
    const float* __restrict__ onsiteE,   // [4,4] -> 4 float4 rows
    float* __restrict__ out,             // [N,4]
    int N)
{
    int n = blockIdx.x * blockDim.x + threadIdx.x;
    if (n >= N) return;
    int a = atype[n];
    const float4* src = (const float4*)onsiteE;
    ((float4*)out)[n] = src[a];
}

extern "C" void kernel_launch(void* const* d_in, const int* in_sizes, int n_in,
                              void* d_out, int out_size, void* d_ws, size_t ws_size,
                              hipStream_t stream) {
    const float* rij       = (const float*)d_in[0];
    const int*   edge_type = (const int*)  d_in[1];
    const int*   atom_type = (const int*)  d_in[2];
    const float* hop_tab   = (const float*)d_in[3];
    const float* ovl_tab   = (const float*)d_in[4];
    const float* onsiteE   = (const float*)d_in[5];

    const int E = in_sizes[0];
    const int N = in_sizes[2];

    float* out_hop  = (float*)d_out;
    float* out_ovl  = out_hop + (size_t)E * NUM_INGRLS;
    float* out_node = out_ovl + (size_t)E * NUM_INGRLS;

    if (d_ws != nullptr && ws_size >= PACKED_BYTES) {
        float* packed = (float*)d_ws;
        {
            int total = N_BOND_TYPES * NGRID * NUM_INGRLS;   // 81,920
            dim3 block(256);
            dim3 grid((total + 255) / 256);
            repack_tables<<<grid, block, 0, stream>>>(hop_tab, ovl_tab, packed);
        }
        {
            dim3 block(256);
            dim3 grid((E + 255) / 256);
            dftb_edge_packed<<<grid, block, 0, stream>>>(
                rij, edge_type, packed, out_hop, out_ovl, E);
        }
    } else {
        dim3 block(256);
        dim3 grid((E + 255) / 256);
        dftb_edge_kernel<<<grid, block, 0, stream>>>(
            rij, edge_type, hop_tab, ovl_tab, out_hop, out_ovl, E);
    }

    {
        dim3 block(256);
        dim3 grid((N + 255) / 256);
        dftb_node_kernel<<<grid, block, 0, stream>>>(
            atom_type, onsiteE, out_node, N);
    }
}

// Round 5
// 305.189 us; speedup vs baseline: 1.5219x; 1.3433x over previous
//
#include <hip/hip_runtime.h>

// DFTB Slater-Koster table interpolation.
// Inputs (setup_inputs order):
//   0: rij            [E=2,000,000] float32
//   1: edge_type      [E]           int32
//   2: atom_type      [N=500,000]   int32
//   3: hopping_tables [10,16,512]   float32
//   4: overlap_tables [10,16,512]   float32
//   5: onsiteE        [4,4]         float32
// Outputs (concatenated flat):
//   edge_features [E,16], edge_overlap [E,16], node_features [N,4]
//
// Strategy:
//  * Tables repacked into workspace as packed[B][G][32] (grid point g:
//    16 hop floats then 16 ovl floats = one 128-B row).
//  * Edge kernel uses 4 threads per edge: thread (e, q) loads 4x16B from
//    rows i0/i0+1 (4 lanes sharing an edge read CONSECUTIVE 16-B chunks of
//    the same row -> 16 distinct lines per gather instr instead of 64),
//    and stores its fx4 at base+16*lane -> fully coalesced 1KB/instr full
//    lines, so nontemporal stores don't amplify (Round-4 lesson: NT +
//    stride-64 partial lines caused WRITE_SIZE 250->396 MB).

#define NGRID 512
#define NUM_INGRLS 16
#define N_BOND_TYPES 10
#define PACKED_FLOATS (N_BOND_TYPES * NGRID * 32)          // 163,840 floats
#define PACKED_BYTES  (PACKED_FLOATS * sizeof(float))      // 655,360 B

typedef float fx4 __attribute__((ext_vector_type(4)));

__global__ __launch_bounds__(256) void repack_tables(
    const float* __restrict__ hop,
    const float* __restrict__ ovl,
    float* __restrict__ packed)
{
    int t = blockIdx.x * blockDim.x + threadIdx.x;
    if (t >= N_BOND_TYPES * NGRID * NUM_INGRLS) return;
    int m = t & (NUM_INGRLS - 1);
    int g = (t >> 4) & (NGRID - 1);
    int b = t >> 13;                       // 16*512 = 8192 = 2^13
    float h = hop[((size_t)b * NUM_INGRLS + m) * NGRID + g];
    float o = ovl[((size_t)b * NUM_INGRLS + m) * NGRID + g];
    size_t row = ((size_t)b * NGRID + g) * 32;
    packed[row + m]      = h;
    packed[row + 16 + m] = o;
}

// 4 threads per edge: thread (e, q) computes components [4q, 4q+4) of both
// hop and ovl outputs for edge e.
__global__ __launch_bounds__(256) void dftb_edge_packed_q(
    const float* __restrict__ rij,
    const int*   __restrict__ etype,
    const float* __restrict__ packed,   // [10][512][32]
    float* __restrict__ out_hop,
    float* __restrict__ out_ovl,
    int E)
{
    const float X0f = 1.0f;
    const float DXf = (float)((10.0 - 1.0) / (NGRID - 1));

    int tid = blockIdx.x * blockDim.x + threadIdx.x;
    int e = tid >> 2;
    int q = tid & 3;
    if (e >= E) return;

    float r = rij[e];
    int   b = etype[e];

    float t  = (r - X0f) / DXf;
    int   i0 = (int)floorf(t);
    i0 = min(max(i0, 0), NGRID - 2);
    float frac = t - (float)i0;
    float w0   = 1.0f - frac;

    const fx4* row = (const fx4*)(packed + ((size_t)b * NGRID + i0) * 32);
    // row[0..3]  : hop @ i0     row[4..7]  : ovl @ i0
    // row[8..11] : hop @ i0+1   row[12..15]: ovl @ i0+1
    fx4 h0 = row[q];
    fx4 o0 = row[4 + q];
    fx4 h1 = row[8 + q];
    fx4 o1 = row[12 + q];

    fx4 hv = h0 * w0 + h1 * frac;
    fx4 ov = o0 * w0 + o1 * frac;

    size_t slot = (size_t)e * 4 + q;      // fx4 index; lane-contiguous
    __builtin_nontemporal_store(hv, (fx4*)out_hop + slot);
    __builtin_nontemporal_store(ov, (fx4*)out_ovl + slot);
}

// Fallback (original layout) if workspace is too small for the packed table.
__global__ __launch_bounds__(256) void dftb_edge_kernel(
    const float* __restrict__ rij,
    const int*   __restrict__ etype,
    const float* __restrict__ hop,
    const float* __restrict__ ovl,
    float* __restrict__ out_hop,
    float* __restrict__ out_ovl,
    int E)
{
    const float X0f = 1.0f;
    const float DXf = (float)((10.0 - 1.0) / (NGRID - 1));

    int e = blockIdx.x * blockDim.x + threadIdx.x;
    if (e >= E) return;

    float r = rij[e];
    int   b = etype[e];

    float t  = (r - X0f) / DXf;
    int   i0 = (int)floorf(t);
    i0 = min(max(i0, 0), NGRID - 2);
    float frac = t - (float)i0;
    float w0   = 1.0f - frac;

    const float* hbase = hop + (size_t)b * (NUM_INGRLS * NGRID) + i0;
    const float* obase = ovl + (size_t)b * (NUM_INGRLS * NGRID) + i0;

    float oh[NUM_INGRLS];
    float oo[NUM_INGRLS];
#pragma unroll
    for (int m = 0; m < NUM_INGRLS; ++m) {
        float y0 = hbase[m * NGRID];
        float y1 = hbase[m * NGRID + 1];
        oh[m] = y0 * w0 + y1 * frac;
        float z0 = obase[m * NGRID];
        float z1 = obase[m * NGRID + 1];
        oo[m] = z0 * w0 + z1 * frac;
    }

    float4* oh4 = (float4*)(out_hop + (size_t)e * NUM_INGRLS);
    float4* oo4 = (float4*)(out_ovl + (size_t)e * NUM_INGRLS);
#pragma unroll
    for (int qq = 0; qq < 4; ++qq) {
        oh4[qq] = make_float4(oh[4*qq+0], oh[4*qq+1], oh[4*qq+2], oh[4*qq+3]);
        oo4[qq] = make_float4(oo[4*qq+0], oo[4*qq+1], oo[4*qq+2], oo[4*qq+3]);
    }
}

__global__ __launch_bounds__(256) void dftb_node_kernel(
    const int*   __restrict__ atype,
    const float* __restrict__ onsiteE,   // [4,4] -> 4 float4 rows
    float* __restrict__ out,             // [N,4]
    int N)
{
    int n = blockIdx.x * blockDim.x + threadIdx.x;
    if (n >= N) return;
    int a = atype[n];
    const float4* src = (const float4*)onsiteE;
    ((float4*)out)[n] = src[a];
}

extern "C" void kernel_launch(void* const* d_in, const int* in_sizes, int n_in,
                              void* d_out, int out_size, void* d_ws, size_t ws_size,
                              hipStream_t stream) {
    const float* rij       = (const float*)d_in[0];
    const int*   edge_type = (const int*)  d_in[1];
    const int*   atom_type = (const int*)  d_in[2];
    const float* hop_tab   = (const float*)d_in[3];
    const float* ovl_tab   = (const float*)d_in[4];
    const float* onsiteE   = (const float*)d_in[5];

    const int E = in_sizes[0];
    const int N = in_sizes[2];

    float* out_hop  = (float*)d_out;
    float* out_ovl  = out_hop + (size_t)E * NUM_INGRLS;
    float* out_node = out_ovl + (size_t)E * NUM_INGRLS;

    if (d_ws != nullptr && ws_size >= PACKED_BYTES) {
        float* packed = (float*)d_ws;
        {
            int total = N_BOND_TYPES * NGRID * NUM_INGRLS;   // 81,920
            dim3 block(256);
            dim3 grid((total + 255) / 256);
            repack_tables<<<grid, block, 0, stream>>>(hop_tab, ovl_tab, packed);
        }
        {
            long long total = 4LL * E;                       // 8,000,000 threads
            dim3 block(256);
            dim3 grid((unsigned)((total + 255) / 256));
            dftb_edge_packed_q<<<grid, block, 0, stream>>>(
                rij, edge_type, packed, out_hop, out_ovl, E);
        }
    } else {
        dim3 block(256);
        dim3 grid((E + 255) / 256);
        dftb_edge_kernel<<<grid, block, 0, stream>>>(
            rij, edge_type, hop_tab, ovl_tab, out_hop, out_ovl, E);
    }

    {
        dim3 block(256);
        dim3 grid((N + 255) / 256);
        dftb_node_kernel<<<grid, block, 0, stream>>>(
            atom_type, onsiteE, out_node, N);
    }
}